// Round 16
// baseline (92.889 us; speedup 1.0000x reference)
//
#include <hip/hip_runtime.h>

typedef __bf16 bf16;
typedef bf16 bf16x2 __attribute__((ext_vector_type(2)));
typedef bf16 bf16x4 __attribute__((ext_vector_type(4)));
typedef bf16 bf16x8 __attribute__((ext_vector_type(8)));
typedef float f32x4 __attribute__((ext_vector_type(4)));
typedef float f32x16 __attribute__((ext_vector_type(16)));
typedef unsigned int u32;
typedef u32 u32x4 __attribute__((ext_vector_type(4)));
typedef float4 f4;

constexpr int BHN = 64;   // B*H
constexpr int LN  = 4096;
constexpr int DN  = 64;
constexpr int MN  = 266;  // real feature rows
constexpr int MP  = 320;  // padded (kernel D stores pad entries as exact 0)
constexpr int STR = 72;   // K/pj LDS stride in bf16 (144B)
constexpr int KVS = 328;  // B's kv LDS stride in bf16
constexpr int TL  = 128;  // kernel A l-tile
constexpr int NLQ = 4;    // L-quarters
constexpr int NTQ = LN / (NLQ * TL);  // 8 tiles per block
#define EPSF 1e-3f

#define MFMA32(A, B, C) __builtin_amdgcn_mfma_f32_32x32x16_bf16(A, B, C, 0, 0, 0)

__device__ __forceinline__ u32 cvt_pk_bf16(float lo, float hi) {
  u32 r;
  asm("v_cvt_pk_bf16_f32 %0, %1, %2" : "=v"(r) : "v"(lo), "v"(hi));
  return r;
}

// transform feature regs (rows=l, col=m lane) -> kv-MFMA B-operand (k=l, col=m)
#define T12_TRANSFORM(f, kb0, kb1)                                   \
  {                                                                  \
    u32 w0 = cvt_pk_bf16(f[0], f[1]);                                \
    u32 w1 = cvt_pk_bf16(f[2], f[3]);                                \
    u32 w2 = cvt_pk_bf16(f[4], f[5]);                                \
    u32 w3 = cvt_pk_bf16(f[6], f[7]);                                \
    u32 w4 = cvt_pk_bf16(f[8], f[9]);                                \
    u32 w5 = cvt_pk_bf16(f[10], f[11]);                              \
    u32 w6 = cvt_pk_bf16(f[12], f[13]);                              \
    u32 w7 = cvt_pk_bf16(f[14], f[15]);                              \
    asm("v_permlane32_swap_b32 %0, %1" : "+v"(w0), "+v"(w2));        \
    asm("v_permlane32_swap_b32 %0, %1" : "+v"(w1), "+v"(w3));        \
    asm("v_permlane32_swap_b32 %0, %1" : "+v"(w4), "+v"(w6));        \
    asm("v_permlane32_swap_b32 %0, %1" : "+v"(w5), "+v"(w7));        \
    u32x4 a0_ = {w0, w1, w2, w3};                                    \
    u32x4 a1_ = {w4, w5, w6, w7};                                    \
    kb0 = __builtin_bit_cast(bf16x8, a0_);                           \
    kb1 = __builtin_bit_cast(bf16x8, a1_);                           \
  }

// ---------------------------------------------------------------------------
// Kernel A (r10-proven v7, session-best configuration): wave-owned output
// slices, deep per-wave work between barriers.
// Grid 256 = (4 lq, 64 bh) -> exactly 1 block/CU. Block = 640 thr = 10 waves,
// wave w = (mc = w%5, h = w/5) owns kv slice [64 d][32 m] in registers for
// the whole kernel; per 128-l tile the wave runs all 4 l-slices
// (32 MFMA32 + 32 ds_read between barriers).
// r11-r15 established: dbuf / raw-barrier / load-reorder / bigger-tile /
// 2-block variants all regress or are null -- staging is BW-bound per tile,
// so schedule reorderings of the same traffic cannot beat this form.
// ---------------------------------------------------------------------------
__global__ __launch_bounds__(640, 2) void perf_kv_fused(
    const float* __restrict__ kg, const float* __restrict__ vg,
    const float* __restrict__ proj, float* __restrict__ kv_part,
    float* __restrict__ ksum_part)
{
  __shared__ __align__(16) bf16 k_lds[TL * STR];   // [128 l][64 d] 18432 B
  __shared__ __align__(16) bf16 vt_lds[64 * 128];  // [64 d][128 l] 16384 B, swizzled

  const int t    = threadIdx.x;
  const int wid  = t >> 6;     // 0..9
  const int lane = t & 63;
  const int ln31 = lane & 31;
  const int hi   = lane >> 5;
  const int mc   = wid % 5;
  const int h    = wid / 5;    // m-half
  const int lq   = blockIdx.x & 3;
  const int bh   = blockIdx.x >> 2;
  const int m0   = mc * 64;

  // proj B-fragments (register-resident): col m = m0+h*32+ln31, k(d)=ks*16+hi*8
  bf16x8 pb[4];
  {
    const int m = m0 + h * 32 + ln31;
#pragma unroll
    for (int ks = 0; ks < 4; ++ks) {
      bf16x8 w = {};
      if (m < MN) {
        const float* p = proj + m * 64 + ks * 16 + hi * 8;
        f4 a = *(const f4*)p;
        f4 b = *(const f4*)(p + 4);
        w = (bf16x8){(bf16)a.x, (bf16)a.y, (bf16)a.z, (bf16)a.w,
                     (bf16)b.x, (bf16)b.y, (bf16)b.z, (bf16)b.w};
      }
      pb[ks] = w;
    }
  }

  f32x16 acc0 = (f32x16){};  // kvT rows d = (r&3)+8*(r>>2)+4*hi, col m
  f32x16 acc1 = (f32x16){};  // kvT rows d = 32 + same,           col m
  float ksum_acc = 0.f;

  const f4* kg4 = (const f4*)kg + ((size_t)bh * LN) * 16;
  const f4* vg4 = (const f4*)vg + ((size_t)bh * LN) * 16;

  f4 kreg[4], vra[2], vrb[2];

  auto LOAD = [&](int tile) {
    const int l0 = (lq * NTQ + tile) * TL;
    if (t < 512) {
#pragma unroll
      for (int i2 = 0; i2 < 4; ++i2) {
        int idx = t + i2 * 512;
        kreg[i2] = kg4[(l0 + (idx >> 4)) * 16 + (idx & 15)];
      }
#pragma unroll
      for (int i2 = 0; i2 < 2; ++i2) {
        int u = t + i2 * 512;
        int lb2 = u >> 4, d4 = u & 15;
        vra[i2] = vg4[(l0 + lb2 * 2) * 16 + d4];
        vrb[i2] = vg4[(l0 + lb2 * 2 + 1) * 16 + d4];
      }
    }
  };
  // swizzled vt addressing (bf16 units): row stride 128, XOR (row&15)<<3
  auto VTW = [&](int r, int c) -> bf16* {
    return &vt_lds[r * 128 + (c ^ ((r & 15) << 3))];
  };
  auto WRITE = [&]() {
    if (t < 512) {
#pragma unroll
      for (int i2 = 0; i2 < 4; ++i2) {
        int idx = t + i2 * 512;
        int row = idx >> 4, d4 = idx & 15;
        f4 val = kreg[i2];
        bf16x4 w = {(bf16)val.x, (bf16)val.y, (bf16)val.z, (bf16)val.w};
        *(bf16x4*)&k_lds[row * STR + d4 * 4] = w;
      }
#pragma unroll
      for (int i2 = 0; i2 < 2; ++i2) {
        int u = t + i2 * 512;
        int lb2 = u >> 4, d4 = u & 15;
        f4 a = vra[i2], b2 = vrb[i2];
        bf16x2 w0 = {(bf16)a.x, (bf16)b2.x};
        bf16x2 w1 = {(bf16)a.y, (bf16)b2.y};
        bf16x2 w2 = {(bf16)a.z, (bf16)b2.z};
        bf16x2 w3 = {(bf16)a.w, (bf16)b2.w};
        *(bf16x2*)VTW(d4 * 4 + 0, lb2 * 2) = w0;
        *(bf16x2*)VTW(d4 * 4 + 1, lb2 * 2) = w1;
        *(bf16x2*)VTW(d4 * 4 + 2, lb2 * 2) = w2;
        *(bf16x2*)VTW(d4 * 4 + 3, lb2 * 2) = w3;
      }
    }
  };

  LOAD(0);
  for (int tile = 0; tile < NTQ; ++tile) {
    __syncthreads();                     // prev tile consumed
    WRITE();                             // (waits vmcnt for this tile's loads)
    if (tile < NTQ - 1) LOAD(tile + 1);  // r10 position (r15 A/B: null)
    __syncthreads();                     // tile ready

#pragma unroll
    for (int s4 = 0; s4 < 4; ++s4) {
      // K A-frags: row l = s4*32+ln31 (local), k(d) = ks*16+hi*8
      bf16x8 ka[4];
#pragma unroll
      for (int ks = 0; ks < 4; ++ks)
        ka[ks] = *(const bf16x8*)&k_lds[(s4 * 32 + ln31) * STR + ks * 16 + hi * 8];
      // V^T A-frags (swizzled read): row d = dt*32+ln31, k(l) = s4*32+kk*16+hi*8
      bf16x8 va00 = *(const bf16x8*)VTW(ln31, s4 * 32 + hi * 8);
      bf16x8 va01 = *(const bf16x8*)VTW(ln31, s4 * 32 + 16 + hi * 8);
      bf16x8 va10 = *(const bf16x8*)VTW(32 + ln31, s4 * 32 + hi * 8);
      bf16x8 va11 = *(const bf16x8*)VTW(32 + ln31, s4 * 32 + 16 + hi * 8);

      // feature: C1[l][m] = K·projT (lane = m col, regs = l rows)
      f32x16 f = (f32x16){};
#pragma unroll
      for (int ks = 0; ks < 4; ++ks) f = MFMA32(ka[ks], pb[ks], f);
#pragma unroll
      for (int i2 = 0; i2 < 16; ++i2) f[i2] = fmaxf(f[i2], 0.f) + EPSF;
      ksum_acc += f[0] + f[1] + f[2] + f[3] + f[4] + f[5] + f[6] + f[7]
                + f[8] + f[9] + f[10] + f[11] + f[12] + f[13] + f[14] + f[15];

      bf16x8 kb0, kb1;
      T12_TRANSFORM(f, kb0, kb1)
      acc0 = MFMA32(va00, kb0, acc0);
      acc0 = MFMA32(va01, kb1, acc0);
      acc1 = MFMA32(va10, kb0, acc1);
      acc1 = MFMA32(va11, kb1, acc1);
    }
  }

  // ---- epilogue: direct single-writer f32 partial stores ----
  {
    const int m = m0 + h * 32 + ln31;
    float* base = kv_part + ((size_t)lq * BHN + bh) * 64 * MP;
#pragma unroll
    for (int r = 0; r < 16; ++r) {
      const int d0 = (r & 3) + 8 * (r >> 2) + 4 * hi;
      base[(size_t)d0 * MP + m] = acc0[r];
      base[(size_t)(32 + d0) * MP + m] = acc1[r];
    }
    float rr = ksum_acc + __shfl_xor(ksum_acc, 32);
    if (hi == 0) ksum_part[((size_t)lq * BHN + bh) * MP + m] = rr;
  }
}

// ---------------------------------------------------------------------------
// Kernel D: sum 4 l-quarter partials -> bf16 kv_b + f32 ksum (pad m -> 0)
// ---------------------------------------------------------------------------
__global__ __launch_bounds__(256) void perf_reduce(
    const float* __restrict__ kv_part, const float* __restrict__ ksum_part,
    bf16* __restrict__ kv_b, float* __restrict__ ksum_ws)
{
  constexpr int KV4 = BHN * DN * MP / 4;         // 327680
  constexpr int KS  = BHN * MP;                  // 20480
  constexpr size_t PS  = (size_t)BHN * DN * MP;  // kv partial stride (f32)
  constexpr size_t PSK = (size_t)BHN * MP;       // ksum partial stride

  int idx = blockIdx.x * 256 + threadIdx.x;
  if (idx < KV4) {
    const f4* p = (const f4*)kv_part;
    f4 v0 = p[idx];
    f4 v1 = p[idx + PS / 4];
    f4 v2 = p[idx + 2 * (PS / 4)];
    f4 v3 = p[idx + 3 * (PS / 4)];
    f4 sv = {v0.x + v1.x + v2.x + v3.x, v0.y + v1.y + v2.y + v3.y,
             v0.z + v1.z + v2.z + v3.z, v0.w + v1.w + v2.w + v3.w};
    int m = (idx * 4) % MP;
    bf16x4 w;
    w[0] = (m + 0 < MN) ? (bf16)sv.x : (bf16)0.f;
    w[1] = (m + 1 < MN) ? (bf16)sv.y : (bf16)0.f;
    w[2] = (m + 2 < MN) ? (bf16)sv.z : (bf16)0.f;
    w[3] = (m + 3 < MN) ? (bf16)sv.w : (bf16)0.f;
    *(bf16x4*)&kv_b[idx * 4] = w;
  } else if (idx < KV4 + KS) {
    int p = idx - KV4;
    int m = p % MP;
    float v = ksum_part[p] + ksum_part[p + PSK] + ksum_part[p + 2 * PSK]
            + ksum_part[p + 3 * PSK];
    ksum_ws[p] = (m < MN) ? v : 0.f;
  }
}

// ---------------------------------------------------------------------------
// Kernel B (r4-verified structure, unchanged)
// ---------------------------------------------------------------------------
__global__ __launch_bounds__(512, 2) void perf_out_mfma32(
    const float* __restrict__ qg, const float* __restrict__ proj,
    const bf16* __restrict__ kvb, const float* __restrict__ ksum_ws,
    float* __restrict__ outg)
{
  __shared__ __align__(16) bf16 pj_lds[MP * STR];   // [m][d]
  __shared__ __align__(16) bf16 kv_lds[DN * KVS];   // [d][m]
  __shared__ __align__(16) float ksum_lds[MP];
  __shared__ float dp_lds[8 * 64];

  const int t    = threadIdx.x;
  const int wid  = t >> 6;
  const int lane = t & 63;
  const int ln31 = lane & 31;
  const int hi   = lane >> 5;
  const int bh   = blockIdx.y;
  const int lbase = blockIdx.x * 1024;

  {
    const f4* projv = (const f4*)proj;
#pragma unroll
    for (int i = 0; i < 10; ++i) {
      int idx = t + i * 512;
      int r = idx >> 4, c4 = idx & 15;
      f4 v = {0.f, 0.f, 0.f, 0.f};
      if (r < MN) v = projv[r * 16 + c4];
      bf16x4 w = {(bf16)v.x, (bf16)v.y, (bf16)v.z, (bf16)v.w};
      *(bf16x4*)&pj_lds[r * STR + c4 * 4] = w;
    }
  }
  for (int idx = t; idx < DN * 40; idx += 512) {
    int r = idx / 40, cc = idx % 40;
    *(bf16x8*)&kv_lds[r * KVS + cc * 8] =
        *(const bf16x8*)&kvb[((size_t)bh * DN + r) * MP + cc * 8];
  }
  if (t < MP) ksum_lds[t] = ksum_ws[bh * MP + t];
  __syncthreads();  // the only block barrier

  for (int rnd = 0; rnd < 2; ++rnd) {
    const int lw = lbase + rnd * 512 + wid * 64;

    bf16x8 qb[2][4];
#pragma unroll
    for (int lt = 0; lt < 2; ++lt)
#pragma unroll
      for (int ks = 0; ks < 4; ++ks) {
        const float* qp_ = qg + ((size_t)bh * LN + lw + lt * 32 + ln31) * 64 + ks * 16 + hi * 8;
        f4 a = *(const f4*)qp_;
        f4 b = *(const f4*)(qp_ + 4);
        qb[lt][ks] = (bf16x8){(bf16)a.x, (bf16)a.y, (bf16)a.z, (bf16)a.w,
                              (bf16)b.x, (bf16)b.y, (bf16)b.z, (bf16)b.w};
      }

    f32x16 oc[2][2];
    oc[0][0] = (f32x16){}; oc[0][1] = (f32x16){};
    oc[1][0] = (f32x16){}; oc[1][1] = (f32x16){};
    float dp[2] = {0.f, 0.f};

    for (int mc = 0; mc < 5; ++mc) {
      f32x16 c2[2][2];
      c2[0][0] = (f32x16){}; c2[0][1] = (f32x16){};
      c2[1][0] = (f32x16){}; c2[1][1] = (f32x16){};
#pragma unroll
      for (int ks = 0; ks < 4; ++ks) {
        bf16x8 pa0 = *(const bf16x8*)&pj_lds[(mc * 64 + ln31) * STR + ks * 16 + hi * 8];
        bf16x8 pa1 = *(const bf16x8*)&pj_lds[(mc * 64 + 32 + ln31) * STR + ks * 16 + hi * 8];
        c2[0][0] = MFMA32(pa0, qb[0][ks], c2[0][0]);
        c2[1][0] = MFMA32(pa0, qb[1][ks], c2[1][0]);
        c2[0][1] = MFMA32(pa1, qb[0][ks], c2[0][1]);
        c2[1][1] = MFMA32(pa1, qb[1][ks], c2[1][1]);
      }
#pragma unroll
      for (int mt = 0; mt < 2; ++mt) {
        const int mb = mc * 64 + mt * 32 + 4 * hi;
        f32x4 kq0 = *(const f32x4*)&ksum_lds[mb + 0];
        f32x4 kq1 = *(const f32x4*)&ksum_lds[mb + 8];
        f32x4 kq2 = *(const f32x4*)&ksum_lds[mb + 16];
        f32x4 kq3 = *(const f32x4*)&ksum_lds[mb + 24];
        bf16x8 A[2][2];
#pragma unroll
        for (int lt = 0; lt < 2; ++lt) {
          f32x16 f = c2[lt][mt];
#pragma unroll
          for (int i = 0; i < 16; ++i) f[i] = fmaxf(f[i], 0.f) + EPSF;
          dp[lt] += f[0] * kq0[0] + f[1] * kq0[1] + f[2] * kq0[2] + f[3] * kq0[3]
                  + f[4] * kq1[0] + f[5] * kq1[1] + f[6] * kq1[2] + f[7] * kq1[3]
                  + f[8] * kq2[0] + f[9] * kq2[1] + f[10] * kq2[2] + f[11] * kq2[3]
                  + f[12] * kq3[0] + f[13] * kq3[1] + f[14] * kq3[2] + f[15] * kq3[3];
          bf16x8 kb0, kb1;
          T12_TRANSFORM(f, kb0, kb1)
          A[lt][0] = kb0;
          A[lt][1] = kb1;
        }
#pragma unroll
        for (int kk = 0; kk < 2; ++kk) {
          const int mo = mc * 64 + (mt * 2 + kk) * 16 + hi * 8;
          bf16x8 kb0 = *(const bf16x8*)&kv_lds[ln31 * KVS + mo];
          bf16x8 kb1 = *(const bf16x8*)&kv_lds[(32 + ln31) * KVS + mo];
          oc[0][0] = MFMA32(A[0][kk], kb0, oc[0][0]);
          oc[1][0] = MFMA32(A[1][kk], kb0, oc[1][0]);
          oc[0][1] = MFMA32(A[0][kk], kb1, oc[0][1]);
          oc[1][1] = MFMA32(A[1][kk], kb1, oc[1][1]);
        }
      }
    }

#pragma unroll
    for (int lt = 0; lt < 2; ++lt) {
      float r = dp[lt];
      r += __shfl_xor(r, 32);
      dp_lds[wid * 64 + lt * 32 + ln31] = r;
    }
#pragma unroll
    for (int lt = 0; lt < 2; ++lt) {
#pragma unroll
      for (int rg = 0; rg < 4; ++rg) {
        f32x4 dv = *(const f32x4*)&dp_lds[wid * 64 + lt * 32 + 8 * rg + 4 * hi];
        f32x4 di = {1.f / dv[0], 1.f / dv[1], 1.f / dv[2], 1.f / dv[3]};
#pragma unroll
        for (int dt = 0; dt < 2; ++dt) {
#pragma unroll
          for (int j = 0; j < 4; ++j) {
            int l = lw + lt * 32 + 8 * rg + 4 * hi + j;
            outg[((size_t)bh * LN + l) * DN + dt * 32 + ln31] = oc[lt][dt][4 * rg + j] * di[j];
          }
        }
      }
    }
  }
}

// ---------------------------------------------------------------------------
extern "C" void kernel_launch(void* const* d_in, const int* in_sizes, int n_in,
                              void* d_out, int out_size, void* d_ws, size_t ws_size,
                              hipStream_t stream)
{
  const float* q    = (const float*)d_in[0];
  const float* k    = (const float*)d_in[1];
  const float* v    = (const float*)d_in[2];
  const float* proj = (const float*)d_in[3];
  float* out = (float*)d_out;

  float* kv_part   = (float*)d_ws;                            // [4][64][64][320] f32
  float* ksum_part = kv_part + (size_t)NLQ * BHN * DN * MP;   // [4][64][320] f32
  float* ksum_ws   = ksum_part + (size_t)NLQ * BHN * MP;      // [64][320] f32
  bf16*  kv_b      = (bf16*)(ksum_ws + (size_t)BHN * MP);     // [64][64][320] bf16
  // All buffers fully written by their single producer -> no memset, no atomics.

  perf_kv_fused<<<NLQ * BHN, 640, 0, stream>>>(k, v, proj, kv_part, ksum_part);

  constexpr int RED_ITEMS = BHN * DN * MP / 4 + BHN * MP;  // 348160
  perf_reduce<<<(RED_ITEMS + 255) / 256, 256, 0, stream>>>(kv_part, ksum_part, kv_b, ksum_ws);

  perf_out_mfma32<<<dim3(LN / 1024, BHN), 512, 0, stream>>>(q, proj, kv_b, ksum_ws, out);
}

// Round 17
// 89.521 us; speedup vs baseline: 1.0376x; 1.0376x over previous
//
#include <hip/hip_runtime.h>

typedef __bf16 bf16;
typedef bf16 bf16x2 __attribute__((ext_vector_type(2)));
typedef bf16 bf16x4 __attribute__((ext_vector_type(4)));
typedef bf16 bf16x8 __attribute__((ext_vector_type(8)));
typedef float f32x4 __attribute__((ext_vector_type(4)));
typedef float f32x16 __attribute__((ext_vector_type(16)));
typedef unsigned int u32;
typedef u32 u32x4 __attribute__((ext_vector_type(4)));
typedef float4 f4;

constexpr int BHN = 64;   // B*H
constexpr int LN  = 4096;
constexpr int DN  = 64;
constexpr int MN  = 266;  // real feature rows
constexpr int MP  = 320;  // padded (pads masked to 0 in B's staging)
constexpr int STR = 72;   // K/pj LDS stride in bf16 (144B)
constexpr int KVS = 328;  // B's kv LDS stride in bf16
constexpr int TL  = 128;  // kernel A l-tile
constexpr int NLQ = 4;    // L-quarters
constexpr int NTQ = LN / (NLQ * TL);  // 8 tiles per block
#define EPSF 1e-3f

#define MFMA32(A, B, C) __builtin_amdgcn_mfma_f32_32x32x16_bf16(A, B, C, 0, 0, 0)

__device__ __forceinline__ u32 cvt_pk_bf16(float lo, float hi) {
  u32 r;
  asm("v_cvt_pk_bf16_f32 %0, %1, %2" : "=v"(r) : "v"(lo), "v"(hi));
  return r;
}

// transform feature regs (rows=l, col=m lane) -> kv-MFMA B-operand (k=l, col=m)
#define T12_TRANSFORM(f, kb0, kb1)                                   \
  {                                                                  \
    u32 w0 = cvt_pk_bf16(f[0], f[1]);                                \
    u32 w1 = cvt_pk_bf16(f[2], f[3]);                                \
    u32 w2 = cvt_pk_bf16(f[4], f[5]);                                \
    u32 w3 = cvt_pk_bf16(f[6], f[7]);                                \
    u32 w4 = cvt_pk_bf16(f[8], f[9]);                                \
    u32 w5 = cvt_pk_bf16(f[10], f[11]);                              \
    u32 w6 = cvt_pk_bf16(f[12], f[13]);                              \
    u32 w7 = cvt_pk_bf16(f[14], f[15]);                              \
    asm("v_permlane32_swap_b32 %0, %1" : "+v"(w0), "+v"(w2));        \
    asm("v_permlane32_swap_b32 %0, %1" : "+v"(w1), "+v"(w3));        \
    asm("v_permlane32_swap_b32 %0, %1" : "+v"(w4), "+v"(w6));        \
    asm("v_permlane32_swap_b32 %0, %1" : "+v"(w5), "+v"(w7));        \
    u32x4 a0_ = {w0, w1, w2, w3};                                    \
    u32x4 a1_ = {w4, w5, w6, w7};                                    \
    kb0 = __builtin_bit_cast(bf16x8, a0_);                           \
    kb1 = __builtin_bit_cast(bf16x8, a1_);                           \
  }

// ---------------------------------------------------------------------------
// Kernel A (r10-proven, session-best; byte-identical to r16): wave-owned
// output slices, deep per-wave work between barriers.
// Grid 256 = (4 lq, 64 bh) -> exactly 1 block/CU. Block = 640 thr = 10 waves,
// wave w = (mc = w%5, h = w/5) owns kv slice [64 d][32 m] in registers.
// r11-r15: dbuf / raw-barrier / load-reorder / bigger-tile / 2-block variants
// all regress or null -- this 2-barrier form is the measured optimum.
// ---------------------------------------------------------------------------
__global__ __launch_bounds__(640, 2) void perf_kv_fused(
    const float* __restrict__ kg, const float* __restrict__ vg,
    const float* __restrict__ proj, float* __restrict__ kv_part,
    float* __restrict__ ksum_part)
{
  __shared__ __align__(16) bf16 k_lds[TL * STR];   // [128 l][64 d] 18432 B
  __shared__ __align__(16) bf16 vt_lds[64 * 128];  // [64 d][128 l] 16384 B, swizzled

  const int t    = threadIdx.x;
  const int wid  = t >> 6;     // 0..9
  const int lane = t & 63;
  const int ln31 = lane & 31;
  const int hi   = lane >> 5;
  const int mc   = wid % 5;
  const int h    = wid / 5;    // m-half
  const int lq   = blockIdx.x & 3;
  const int bh   = blockIdx.x >> 2;
  const int m0   = mc * 64;

  // proj B-fragments (register-resident): col m = m0+h*32+ln31, k(d)=ks*16+hi*8
  bf16x8 pb[4];
  {
    const int m = m0 + h * 32 + ln31;
#pragma unroll
    for (int ks = 0; ks < 4; ++ks) {
      bf16x8 w = {};
      if (m < MN) {
        const float* p = proj + m * 64 + ks * 16 + hi * 8;
        f4 a = *(const f4*)p;
        f4 b = *(const f4*)(p + 4);
        w = (bf16x8){(bf16)a.x, (bf16)a.y, (bf16)a.z, (bf16)a.w,
                     (bf16)b.x, (bf16)b.y, (bf16)b.z, (bf16)b.w};
      }
      pb[ks] = w;
    }
  }

  f32x16 acc0 = (f32x16){};  // kvT rows d = (r&3)+8*(r>>2)+4*hi, col m
  f32x16 acc1 = (f32x16){};  // kvT rows d = 32 + same,           col m
  float ksum_acc = 0.f;

  const f4* kg4 = (const f4*)kg + ((size_t)bh * LN) * 16;
  const f4* vg4 = (const f4*)vg + ((size_t)bh * LN) * 16;

  f4 kreg[4], vra[2], vrb[2];

  auto LOAD = [&](int tile) {
    const int l0 = (lq * NTQ + tile) * TL;
    if (t < 512) {
#pragma unroll
      for (int i2 = 0; i2 < 4; ++i2) {
        int idx = t + i2 * 512;
        kreg[i2] = kg4[(l0 + (idx >> 4)) * 16 + (idx & 15)];
      }
#pragma unroll
      for (int i2 = 0; i2 < 2; ++i2) {
        int u = t + i2 * 512;
        int lb2 = u >> 4, d4 = u & 15;
        vra[i2] = vg4[(l0 + lb2 * 2) * 16 + d4];
        vrb[i2] = vg4[(l0 + lb2 * 2 + 1) * 16 + d4];
      }
    }
  };
  // swizzled vt addressing (bf16 units): row stride 128, XOR (row&15)<<3
  auto VTW = [&](int r, int c) -> bf16* {
    return &vt_lds[r * 128 + (c ^ ((r & 15) << 3))];
  };
  auto WRITE = [&]() {
    if (t < 512) {
#pragma unroll
      for (int i2 = 0; i2 < 4; ++i2) {
        int idx = t + i2 * 512;
        int row = idx >> 4, d4 = idx & 15;
        f4 val = kreg[i2];
        bf16x4 w = {(bf16)val.x, (bf16)val.y, (bf16)val.z, (bf16)val.w};
        *(bf16x4*)&k_lds[row * STR + d4 * 4] = w;
      }
#pragma unroll
      for (int i2 = 0; i2 < 2; ++i2) {
        int u = t + i2 * 512;
        int lb2 = u >> 4, d4 = u & 15;
        f4 a = vra[i2], b2 = vrb[i2];
        bf16x2 w0 = {(bf16)a.x, (bf16)b2.x};
        bf16x2 w1 = {(bf16)a.y, (bf16)b2.y};
        bf16x2 w2 = {(bf16)a.z, (bf16)b2.z};
        bf16x2 w3 = {(bf16)a.w, (bf16)b2.w};
        *(bf16x2*)VTW(d4 * 4 + 0, lb2 * 2) = w0;
        *(bf16x2*)VTW(d4 * 4 + 1, lb2 * 2) = w1;
        *(bf16x2*)VTW(d4 * 4 + 2, lb2 * 2) = w2;
        *(bf16x2*)VTW(d4 * 4 + 3, lb2 * 2) = w3;
      }
    }
  };

  LOAD(0);
  for (int tile = 0; tile < NTQ; ++tile) {
    __syncthreads();                     // prev tile consumed
    WRITE();                             // (waits vmcnt for this tile's loads)
    if (tile < NTQ - 1) LOAD(tile + 1);  // r10 position (r15 A/B: null)
    __syncthreads();                     // tile ready

#pragma unroll
    for (int s4 = 0; s4 < 4; ++s4) {
      // K A-frags: row l = s4*32+ln31 (local), k(d) = ks*16+hi*8
      bf16x8 ka[4];
#pragma unroll
      for (int ks = 0; ks < 4; ++ks)
        ka[ks] = *(const bf16x8*)&k_lds[(s4 * 32 + ln31) * STR + ks * 16 + hi * 8];
      // V^T A-frags (swizzled read): row d = dt*32+ln31, k(l) = s4*32+kk*16+hi*8
      bf16x8 va00 = *(const bf16x8*)VTW(ln31, s4 * 32 + hi * 8);
      bf16x8 va01 = *(const bf16x8*)VTW(ln31, s4 * 32 + 16 + hi * 8);
      bf16x8 va10 = *(const bf16x8*)VTW(32 + ln31, s4 * 32 + hi * 8);
      bf16x8 va11 = *(const bf16x8*)VTW(32 + ln31, s4 * 32 + 16 + hi * 8);

      // feature: C1[l][m] = K·projT (lane = m col, regs = l rows)
      f32x16 f = (f32x16){};
#pragma unroll
      for (int ks = 0; ks < 4; ++ks) f = MFMA32(ka[ks], pb[ks], f);
#pragma unroll
      for (int i2 = 0; i2 < 16; ++i2) f[i2] = fmaxf(f[i2], 0.f) + EPSF;
      ksum_acc += f[0] + f[1] + f[2] + f[3] + f[4] + f[5] + f[6] + f[7]
                + f[8] + f[9] + f[10] + f[11] + f[12] + f[13] + f[14] + f[15];

      bf16x8 kb0, kb1;
      T12_TRANSFORM(f, kb0, kb1)
      acc0 = MFMA32(va00, kb0, acc0);
      acc0 = MFMA32(va01, kb1, acc0);
      acc1 = MFMA32(va10, kb0, acc1);
      acc1 = MFMA32(va11, kb1, acc1);
    }
  }

  // ---- epilogue: direct single-writer f32 partial stores ----
  {
    const int m = m0 + h * 32 + ln31;
    float* base = kv_part + ((size_t)lq * BHN + bh) * 64 * MP;
#pragma unroll
    for (int r = 0; r < 16; ++r) {
      const int d0 = (r & 3) + 8 * (r >> 2) + 4 * hi;
      base[(size_t)d0 * MP + m] = acc0[r];
      base[(size_t)(32 + d0) * MP + m] = acc1[r];
    }
    float rr = ksum_acc + __shfl_xor(ksum_acc, 32);
    if (hi == 0) ksum_part[((size_t)lq * BHN + bh) * MP + m] = rr;
  }
}

// ---------------------------------------------------------------------------
// Kernel B (r4-verified compute structure) + fused D: staging reads the 4
// l-quarter f32 partials directly, sums, converts to bf16, masks pads -> 0.
// Kernel D is deleted. Grid: 1-D 256 with XCD-swizzle so the 4 blocks of one
// bh share id%8 (same XCD) -> partial re-reads are L2-hot (327KB/bh << 4MB).
// ---------------------------------------------------------------------------
__global__ __launch_bounds__(512, 2) void perf_out_mfma32(
    const float* __restrict__ qg, const float* __restrict__ proj,
    const float* __restrict__ kv_part, const float* __restrict__ ksum_part,
    float* __restrict__ outg)
{
  __shared__ __align__(16) bf16 pj_lds[MP * STR];   // [m][d]
  __shared__ __align__(16) bf16 kv_lds[DN * KVS];   // [d][m]
  __shared__ __align__(16) float ksum_lds[MP];
  __shared__ float dp_lds[8 * 64];

  const int t    = threadIdx.x;
  const int wid  = t >> 6;
  const int lane = t & 63;
  const int ln31 = lane & 31;
  const int hi   = lane >> 5;

  // XCD-swizzled block map: id%8 = bh%8 (XCD), so same-bh blocks co-reside.
  const int id   = blockIdx.x;               // 0..255
  const int xcd  = id & 7, slot = id >> 3;    // slot 0..31
  const int bh   = xcd + (slot >> 2) * 8;     // 0..63
  const int lb   = slot & 3;                  // l-quarter 0..3
  const int lbase = lb * 1024;

  // stage proj f32 -> bf16 (zero-padded m >= 266); constant trip (10)
  {
    const f4* projv = (const f4*)proj;
#pragma unroll
    for (int i = 0; i < 10; ++i) {
      int idx = t + i * 512;
      int r = idx >> 4, c4 = idx & 15;
      f4 v = {0.f, 0.f, 0.f, 0.f};
      if (r < MN) v = projv[r * 16 + c4];
      bf16x4 w = {(bf16)v.x, (bf16)v.y, (bf16)v.z, (bf16)v.w};
      *(bf16x4*)&pj_lds[r * STR + c4 * 4] = w;
    }
  }
  // stage kv: sum 4 f32 partials -> bf16 (pads -> 0); constant trip (5)
  {
    constexpr size_t LQS = (size_t)BHN * DN * MP;   // f32 elems per lq partial
    const float* base = kv_part + (size_t)bh * DN * MP;
#pragma unroll
    for (int i = 0; i < 5; ++i) {
      int idx = t + i * 512;                        // 0..2559
      int r = idx / 40, cc = idx % 40;              // d=r, m = cc*8..+7
      const float* p = base + (size_t)r * MP + cc * 8;
      f4 a0 = *(const f4*)(p);            f4 b0 = *(const f4*)(p + 4);
      f4 a1 = *(const f4*)(p + LQS);      f4 b1 = *(const f4*)(p + LQS + 4);
      f4 a2 = *(const f4*)(p + 2 * LQS);  f4 b2 = *(const f4*)(p + 2 * LQS + 4);
      f4 a3 = *(const f4*)(p + 3 * LQS);  f4 b3 = *(const f4*)(p + 3 * LQS + 4);
      float s[8] = {a0.x + a1.x + a2.x + a3.x, a0.y + a1.y + a2.y + a3.y,
                    a0.z + a1.z + a2.z + a3.z, a0.w + a1.w + a2.w + a3.w,
                    b0.x + b1.x + b2.x + b3.x, b0.y + b1.y + b2.y + b3.y,
                    b0.z + b1.z + b2.z + b3.z, b0.w + b1.w + b2.w + b3.w};
      const int mbase = cc * 8;
      bf16x8 w;
#pragma unroll
      for (int j = 0; j < 8; ++j)
        w[j] = (mbase + j < MN) ? (bf16)s[j] : (bf16)0.f;
      *(bf16x8*)&kv_lds[r * KVS + cc * 8] = w;
    }
  }
  // stage ksum: sum 4 partials (pads -> 0)
  if (t < MP) {
    constexpr size_t LQK = (size_t)BHN * MP;
    const float* p = ksum_part + (size_t)bh * MP + t;
    float v = p[0] + p[LQK] + p[2 * LQK] + p[3 * LQK];
    ksum_lds[t] = (t < MN) ? v : 0.f;
  }
  __syncthreads();  // the only block barrier

  for (int rnd = 0; rnd < 2; ++rnd) {
    const int lw = lbase + rnd * 512 + wid * 64;

    bf16x8 qb[2][4];
#pragma unroll
    for (int lt = 0; lt < 2; ++lt)
#pragma unroll
      for (int ks = 0; ks < 4; ++ks) {
        const float* qp_ = qg + ((size_t)bh * LN + lw + lt * 32 + ln31) * 64 + ks * 16 + hi * 8;
        f4 a = *(const f4*)qp_;
        f4 b = *(const f4*)(qp_ + 4);
        qb[lt][ks] = (bf16x8){(bf16)a.x, (bf16)a.y, (bf16)a.z, (bf16)a.w,
                              (bf16)b.x, (bf16)b.y, (bf16)b.z, (bf16)b.w};
      }

    f32x16 oc[2][2];
    oc[0][0] = (f32x16){}; oc[0][1] = (f32x16){};
    oc[1][0] = (f32x16){}; oc[1][1] = (f32x16){};
    float dp[2] = {0.f, 0.f};

    for (int mc = 0; mc < 5; ++mc) {
      f32x16 c2[2][2];
      c2[0][0] = (f32x16){}; c2[0][1] = (f32x16){};
      c2[1][0] = (f32x16){}; c2[1][1] = (f32x16){};
#pragma unroll
      for (int ks = 0; ks < 4; ++ks) {
        bf16x8 pa0 = *(const bf16x8*)&pj_lds[(mc * 64 + ln31) * STR + ks * 16 + hi * 8];
        bf16x8 pa1 = *(const bf16x8*)&pj_lds[(mc * 64 + 32 + ln31) * STR + ks * 16 + hi * 8];
        c2[0][0] = MFMA32(pa0, qb[0][ks], c2[0][0]);
        c2[1][0] = MFMA32(pa0, qb[1][ks], c2[1][0]);
        c2[0][1] = MFMA32(pa1, qb[0][ks], c2[0][1]);
        c2[1][1] = MFMA32(pa1, qb[1][ks], c2[1][1]);
      }
#pragma unroll
      for (int mt = 0; mt < 2; ++mt) {
        const int mb = mc * 64 + mt * 32 + 4 * hi;
        f32x4 kq0 = *(const f32x4*)&ksum_lds[mb + 0];
        f32x4 kq1 = *(const f32x4*)&ksum_lds[mb + 8];
        f32x4 kq2 = *(const f32x4*)&ksum_lds[mb + 16];
        f32x4 kq3 = *(const f32x4*)&ksum_lds[mb + 24];
        bf16x8 A[2][2];
#pragma unroll
        for (int lt = 0; lt < 2; ++lt) {
          f32x16 f = c2[lt][mt];
#pragma unroll
          for (int i = 0; i < 16; ++i) f[i] = fmaxf(f[i], 0.f) + EPSF;
          dp[lt] += f[0] * kq0[0] + f[1] * kq0[1] + f[2] * kq0[2] + f[3] * kq0[3]
                  + f[4] * kq1[0] + f[5] * kq1[1] + f[6] * kq1[2] + f[7] * kq1[3]
                  + f[8] * kq2[0] + f[9] * kq2[1] + f[10] * kq2[2] + f[11] * kq2[3]
                  + f[12] * kq3[0] + f[13] * kq3[1] + f[14] * kq3[2] + f[15] * kq3[3];
          bf16x8 kb0, kb1;
          T12_TRANSFORM(f, kb0, kb1)
          A[lt][0] = kb0;
          A[lt][1] = kb1;
        }
#pragma unroll
        for (int kk = 0; kk < 2; ++kk) {
          const int mo = mc * 64 + (mt * 2 + kk) * 16 + hi * 8;
          bf16x8 kb0 = *(const bf16x8*)&kv_lds[ln31 * KVS + mo];
          bf16x8 kb1 = *(const bf16x8*)&kv_lds[(32 + ln31) * KVS + mo];
          oc[0][0] = MFMA32(A[0][kk], kb0, oc[0][0]);
          oc[1][0] = MFMA32(A[1][kk], kb0, oc[1][0]);
          oc[0][1] = MFMA32(A[0][kk], kb1, oc[0][1]);
          oc[1][1] = MFMA32(A[1][kk], kb1, oc[1][1]);
        }
      }
    }

#pragma unroll
    for (int lt = 0; lt < 2; ++lt) {
      float r = dp[lt];
      r += __shfl_xor(r, 32);
      dp_lds[wid * 64 + lt * 32 + ln31] = r;
    }
#pragma unroll
    for (int lt = 0; lt < 2; ++lt) {
#pragma unroll
      for (int rg = 0; rg < 4; ++rg) {
        f32x4 dv = *(const f32x4*)&dp_lds[wid * 64 + lt * 32 + 8 * rg + 4 * hi];
        f32x4 di = {1.f / dv[0], 1.f / dv[1], 1.f / dv[2], 1.f / dv[3]};
#pragma unroll
        for (int dt = 0; dt < 2; ++dt) {
#pragma unroll
          for (int j = 0; j < 4; ++j) {
            int l = lw + lt * 32 + 8 * rg + 4 * hi + j;
            outg[((size_t)bh * LN + l) * DN + dt * 32 + ln31] = oc[lt][dt][4 * rg + j] * di[j];
          }
        }
      }
    }
  }
}

// ---------------------------------------------------------------------------
extern "C" void kernel_launch(void* const* d_in, const int* in_sizes, int n_in,
                              void* d_out, int out_size, void* d_ws, size_t ws_size,
                              hipStream_t stream)
{
  const float* q    = (const float*)d_in[0];
  const float* k    = (const float*)d_in[1];
  const float* v    = (const float*)d_in[2];
  const float* proj = (const float*)d_in[3];
  float* out = (float*)d_out;

  float* kv_part   = (float*)d_ws;                            // [4][64][64][320] f32
  float* ksum_part = kv_part + (size_t)NLQ * BHN * DN * MP;   // [4][64][320] f32
  // Both fully written by perf_kv_fused (single writer) -> no memset/atomics.
  // Kernel D deleted: B sums the partials during its staging phase.

  perf_kv_fused<<<NLQ * BHN, 640, 0, stream>>>(k, v, proj, kv_part, ksum_part);
  perf_out_mfma32<<<256, 512, 0, stream>>>(q, proj, kv_part, ksum_part, out);
}